// Round 5
// baseline (273.235 us; speedup 1.0000x reference)
//
#include <hip/hip_runtime.h>

// PhysicsPriorGenerator, fused single kernel (round-1 structure = best measured) +
// nontemporal stores (L2-bypass hint) for the 268 MB write-once output stream.
//   out[pb][j][a] = exp2(K2*(DEPTHS[j]-dt_a)^2) * inv_a
//   dt_a = d/cos((th+ang_a)*pi/180); inv_a = valid ? 1/sum_j exp2(...) : 0
// Store roofline: 268 MB @ ~6.6 TB/s (measured fill rate) ~= 41 us.

#define DD 512
#define AA 256
#define K2 (-2.8853900817779268f)        // -2*log2(e): sigma=0.5 -> exponent -2*diff^2
#define DSTEP (50.0f / 511.0f)
#define ASTEP (60.0f / 255.0f)

typedef float v4f __attribute__((ext_vector_type(4)));   // clang vector: valid for nontemporal builtin

__global__ __launch_bounds__(256) void prior_kernel(const float* __restrict__ p0,
                                                    const float* __restrict__ p1,
                                                    float* __restrict__ out) {
    const int blk = blockIdx.x;            // 0..511; even -> prior0, odd -> prior1 (interleave)
    const int b   = blk >> 1;
    const int pb  = (blk & 1) * 256 + b;
    const float* __restrict__ pp = (blk & 1) ? p1 : p0;

    __shared__ __align__(16) float dt_s[AA];
    __shared__ __align__(16) float inv_s[AA];

    const float d  = pp[b * 3 + 1];
    const float th = pp[b * 3 + 2];

    const int t = threadIdx.x;

    // ---- Phase 1: per-angle column sums (thread t -> angle t) ----
    {
        const float ang = -30.0f + (float)t * ASTEP;
        const float rad = (th + ang) * 0.017453292519943295f;
        const float dt  = d / cosf(rad);
        const bool valid = (dt > 0.0f) && (dt < 50.0f);
        float s0 = 0.0f, s1 = 0.0f, s2 = 0.0f, s3 = 0.0f;
        #pragma unroll 4
        for (int j = 0; j < DD; j += 4) {
            float x0 = (float)(j + 0) * DSTEP - dt;
            float x1 = (float)(j + 1) * DSTEP - dt;
            float x2 = (float)(j + 2) * DSTEP - dt;
            float x3 = (float)(j + 3) * DSTEP - dt;
            s0 += __builtin_amdgcn_exp2f(K2 * x0 * x0);
            s1 += __builtin_amdgcn_exp2f(K2 * x1 * x1);
            s2 += __builtin_amdgcn_exp2f(K2 * x2 * x2);
            s3 += __builtin_amdgcn_exp2f(K2 * x3 * x3);
        }
        const float sum = (s0 + s1) + (s2 + s3);
        const float den = (sum > 0.0f) ? sum : 1.0f;
        inv_s[t] = valid ? (1.0f / den) : 0.0f;
        dt_s[t]  = valid ? dt : 1.0e9f;   // clamped dt -> exp underflows to 0, stays finite
    }
    __syncthreads();

    // ---- Phase 2: normalized writes, float4 nontemporal, coalesced along angle ----
    const int a4   = (t & 63) * 4;
    const int jblk = t >> 6;
    const float dt0 = dt_s[a4 + 0], dt1 = dt_s[a4 + 1], dt2 = dt_s[a4 + 2], dt3 = dt_s[a4 + 3];
    const float i0  = inv_s[a4 + 0], i1 = inv_s[a4 + 1], i2 = inv_s[a4 + 2], i3 = inv_s[a4 + 3];

    float* __restrict__ outp = out + (size_t)pb * (DD * AA) + a4;
    const int j0 = jblk * (DD / 4);
    #pragma unroll 4
    for (int j = j0; j < j0 + DD / 4; ++j) {
        const float dep = (float)j * DSTEP;
        v4f v;
        float dx = dep - dt0; v.x = __builtin_amdgcn_exp2f(K2 * dx * dx) * i0;
        float dy = dep - dt1; v.y = __builtin_amdgcn_exp2f(K2 * dy * dy) * i1;
        float dz = dep - dt2; v.z = __builtin_amdgcn_exp2f(K2 * dz * dz) * i2;
        float dw = dep - dt3; v.w = __builtin_amdgcn_exp2f(K2 * dw * dw) * i3;
        __builtin_nontemporal_store(v, (v4f*)(outp + (size_t)j * AA));
    }
}

extern "C" void kernel_launch(void* const* d_in, const int* in_sizes, int n_in,
                              void* d_out, int out_size, void* d_ws, size_t ws_size,
                              hipStream_t stream) {
    const float* p0 = (const float*)d_in[0];   // p        (256 x 3)
    const float* p1 = (const float*)d_in[1];   // p_calib  (256 x 3)
    float* out = (float*)d_out;                // 2 x 256 x 512 x 256 fp32
    prior_kernel<<<dim3(2 * 256), dim3(256), 0, stream>>>(p0, p1, out);
}